// Round 4
// baseline (248.260 us; speedup 1.0000x reference)
//
#include <hip/hip_runtime.h>
#include <math.h>

#define BETA  0.125f    // 1/sqrt(64)
#define SHIFT 30.0f     // fixed softmax shift; logits bounded in [0.125, 68.5]
#define EPSF  1e-7f
#define EPSD  1e-7

__device__ __forceinline__ float bf16hi(unsigned int u) {
  return __uint_as_float(u & 0xffff0000u);
}
__device__ __forceinline__ float bf16lo(unsigned int u) {
  return __uint_as_float(u << 16);
}
__device__ __forceinline__ unsigned int pack_bf16(float lo, float hi) {
  unsigned int ul = __float_as_uint(lo);
  unsigned int uh = __float_as_uint(hi);
  ul = (ul + 0x7fffu + ((ul >> 16) & 1u)) >> 16;   // RNE
  uh = (uh + 0x7fffu + ((uh >> 16) & 1u)) & 0xffff0000u;
  return ul | uh;
}

// ---------------------------------------------------------------------------
// Merged projection kernel. Blocks 0..63: Q path; 64..191: K path;
// 192..319: V path (double projection). 64x64 output tile per block,
// XOR-swizzled LDS, register-resident expmap epilogue.
// ---------------------------------------------------------------------------
__global__ __launch_bounds__(256) void proj_kernel(
    const float* __restrict__ Xq, const float* __restrict__ Xk,
    const float* __restrict__ Xv,
    const float* __restrict__ Wq, const float* __restrict__ bq,
    const float* __restrict__ Wk, const float* __restrict__ bk,
    const float* __restrict__ Wv, const float* __restrict__ bv,
    float* __restrict__ Q0, float* __restrict__ Qr,
    float* __restrict__ K0, float* __restrict__ Kr,
    float* __restrict__ V0, float* __restrict__ Vr)
{
  __shared__ float Xs[64 * 64];
  __shared__ float Ws[64 * 64];

  const int bid = blockIdx.x;
  const float *X, *W, *bias;
  float *y0, *yr;
  bool dbl;
  int rowBase;
  if (bid < 64)       { X = Xq; W = Wq; bias = bq; y0 = Q0; yr = Qr; rowBase = bid << 6;         dbl = false; }
  else if (bid < 192) { X = Xk; W = Wk; bias = bk; y0 = K0; yr = Kr; rowBase = (bid - 64) << 6;  dbl = false; }
  else                { X = Xv; W = Wk; bias = bk; y0 = V0; yr = Vr; rowBase = (bid - 192) << 6; dbl = true;  }

  const int tid = threadIdx.x;
  const int ty = tid >> 4, tx = tid & 15;
  const int ty4 = ty << 2, tx4 = tx << 2;

  float acc[4][4];
#pragma unroll
  for (int j = 0; j < 4; ++j) {
    float bj = bias[tx4 + j];
#pragma unroll
    for (int i = 0; i < 4; ++i) acc[i][j] = bj;
  }

  for (int kc = 0; kc < 4; ++kc) {
#pragma unroll
    for (int q = 0; q < 4; ++q) {
      int f = tid + (q << 8);
      int r = f >> 4, g = f & 15;
      int sw = (r << 6) + ((g ^ (r >> 2)) << 2);
      *(float4*)&Xs[sw] = *(const float4*)&X[(rowBase + r) * 256 + (kc << 6) + (g << 2)];
      *(float4*)&Ws[sw] = *(const float4*)&W[r * 256 + (kc << 6) + (g << 2)];
    }
    __syncthreads();
#pragma unroll 4
    for (int kk = 0; kk < 64; kk += 4) {
      const int gk = kk >> 2;
      float4 xa[4], wb[4];
#pragma unroll
      for (int i = 0; i < 4; ++i)
        xa[i] = *(const float4*)&Xs[((ty4 + i) << 6) + ((gk ^ ty) << 2)];
#pragma unroll
      for (int j = 0; j < 4; ++j)
        wb[j] = *(const float4*)&Ws[((tx4 + j) << 6) + ((gk ^ tx) << 2)];
#pragma unroll
      for (int i = 0; i < 4; ++i)
#pragma unroll
        for (int j = 0; j < 4; ++j)
          acc[i][j] += xa[i].x * wb[j].x + xa[i].y * wb[j].y +
                       xa[i].z * wb[j].z + xa[i].w * wb[j].w;
    }
    __syncthreads();
  }

  if (dbl) {
#pragma unroll
    for (int i = 0; i < 4; ++i) {
      float4 v = make_float4(acc[i][0], acc[i][1], acc[i][2], acc[i][3]);
      *(float4*)&Xs[((ty4 + i) << 6) + ((tx ^ ty) << 2)] = v;
    }
#pragma unroll
    for (int q = 0; q < 4; ++q) {
      int f = tid + (q << 8);
      int r = f >> 4, g = f & 15;
      int sw = (r << 6) + ((g ^ (r >> 2)) << 2);
      *(float4*)&Ws[sw] = *(const float4*)&Wv[(r << 6) + (g << 2)];
    }
#pragma unroll
    for (int j = 0; j < 4; ++j) {
      float bj = bv[tx4 + j];
#pragma unroll
      for (int i = 0; i < 4; ++i) acc[i][j] = bj;
    }
    __syncthreads();
#pragma unroll 4
    for (int kk = 0; kk < 64; kk += 4) {
      const int gk = kk >> 2;
      float4 xa[4], wb[4];
#pragma unroll
      for (int i = 0; i < 4; ++i)
        xa[i] = *(const float4*)&Xs[((ty4 + i) << 6) + ((gk ^ ty) << 2)];
#pragma unroll
      for (int j = 0; j < 4; ++j)
        wb[j] = *(const float4*)&Ws[((tx4 + j) << 6) + ((gk ^ tx) << 2)];
#pragma unroll
      for (int i = 0; i < 4; ++i)
#pragma unroll
        for (int j = 0; j < 4; ++j)
          acc[i][j] += xa[i].x * wb[j].x + xa[i].y * wb[j].y +
                       xa[i].z * wb[j].z + xa[i].w * wb[j].w;
    }
  }

  // expmap0 epilogue in registers + shuffles
  float n2p[4];
#pragma unroll
  for (int i = 0; i < 4; ++i)
    n2p[i] = acc[i][0] * acc[i][0] + acc[i][1] * acc[i][1] +
             acc[i][2] * acc[i][2] + acc[i][3] * acc[i][3];
#pragma unroll
  for (int i = 0; i < 4; ++i) {
    n2p[i] += __shfl_xor(n2p[i], 1);
    n2p[i] += __shfl_xor(n2p[i], 2);
    n2p[i] += __shfl_xor(n2p[i], 4);
    n2p[i] += __shfl_xor(n2p[i], 8);
  }
#pragma unroll
  for (int i = 0; i < 4; ++i) {
    float n = sqrtf(n2p[i]);
    float factor = fminf(3.5f / (n + EPSF), 1.0f);
    float xn = fmaxf(n * factor, EPSF);
    float et = __expf(xn);
    float rt = __builtin_amdgcn_rcpf(et);
    float ch = 0.5f * (et + rt);
    float sh = 0.5f * (et - rt);
    float scale = sh * factor * __builtin_amdgcn_rcpf(xn);
    if (tx == 0) y0[rowBase + ty4 + i] = ch;
    float4 v = make_float4(acc[i][0] * scale, acc[i][1] * scale,
                           acc[i][2] * scale, acc[i][3] * scale);
    *(float4*)&yr[(rowBase + ty4 + i) * 64 + tx4] = v;
  }
}

// ---------------------------------------------------------------------------
// Attention core. Tile 128 s-rows x 64 m-chunk; 8x4 register blocking.
// Grid (16 s-tiles, SL slices, 2 batches). LDS = Q 32K + K 16K + V 16K = 64K
// exactly (2 WGs/CU). Weight tile (bf16 128x64 = 16K) overlays Ks in Phase B.
// Q0/K0/V0 kept in registers. Hardwired identities: w = e*acosh(-c)*rsq(c^2-1).
// ---------------------------------------------------------------------------
__global__ __launch_bounds__(256, 2) void attn_kernel(
    const float* __restrict__ Q0g, const float* __restrict__ Qrg,
    const float* __restrict__ K0g, const float* __restrict__ Krg,
    const float* __restrict__ V0g, const float* __restrict__ Vrg,
    float* __restrict__ Tpart, float* __restrict__ T0part,
    float* __restrict__ Lpart, float* __restrict__ WCpart, int nChunk)
{
  __shared__ float Qs[128 * 64];  // 32 KB, swizzle: group g at g ^ ((r>>3)&3)
  __shared__ float Ks[64 * 64];   // 16 KB, swizzle g ^ (r>>2); W (bf16) overlay
  __shared__ float Vs[64 * 64];   // 16 KB, swizzle g ^ (r>>2)

  const int tid = threadIdx.x;
  const int ty = tid >> 4, tx = tid & 15;
  const int ty8 = ty << 3, tx4 = tx << 2;
  const int tym = ty & 3;
  const int b = blockIdx.z;
  const int sl = blockIdx.y;
  const int rowQ = (b << 11) + (blockIdx.x << 7);

  // stage Q tile (128 x 64)
#pragma unroll
  for (int q = 0; q < 8; ++q) {
    int f = tid + (q << 8);
    int r = f >> 4, g = f & 15;
    int sw = (r << 6) + ((g ^ ((r >> 3) & 3)) << 2);
    *(float4*)&Qs[sw] = *(const float4*)&Qrg[(rowQ + r) * 64 + (g << 2)];
  }
  float q0r[8];
#pragma unroll
  for (int i = 0; i < 8; ++i) q0r[i] = Q0g[rowQ + ty8 + i];

  float accT[8][4], Lp[8], WCp[8], T0p[8];
#pragma unroll
  for (int i = 0; i < 8; ++i) {
    Lp[i] = 0.f; WCp[i] = 0.f; T0p[i] = 0.f;
#pragma unroll
    for (int j = 0; j < 4; ++j) accT[i][j] = 0.f;
  }
  __syncthreads();

  const int mBase = (b << 12) + sl * (nChunk << 6);
  for (int mc = 0; mc < nChunk; ++mc) {
    const int mG = mBase + (mc << 6);
#pragma unroll
    for (int q = 0; q < 4; ++q) {
      int f = tid + (q << 8);
      int r = f >> 4, g = f & 15;
      int sw = (r << 6) + ((g ^ (r >> 2)) << 2);
      *(float4*)&Ks[sw] = *(const float4*)&Krg[(mG + r) * 64 + (g << 2)];
      *(float4*)&Vs[sw] = *(const float4*)&Vrg[(mG + r) * 64 + (g << 2)];
    }
    float k0r[4], v0r[4];
#pragma unroll
    for (int j = 0; j < 4; ++j) {
      k0r[j] = K0g[mG + tx4 + j];
      v0r[j] = V0g[mG + tx4 + j];
    }
    __syncthreads();

    // Phase A: dual Minkowski dots
    float sims[8][4], ipv[8][4];
#pragma unroll
    for (int i = 0; i < 8; ++i)
#pragma unroll
      for (int j = 0; j < 4; ++j) {
        sims[i][j] = -q0r[i] * k0r[j];
        ipv[i][j]  = -q0r[i] * v0r[j];
      }
#pragma unroll 4
    for (int kk = 0; kk < 64; kk += 4) {
      const int gk = kk >> 2;
      float4 ka[4], va[4];
#pragma unroll
      for (int j = 0; j < 4; ++j) {
        int base = ((tx4 + j) << 6) + ((gk ^ tx) << 2);
        ka[j] = *(const float4*)&Ks[base];
        va[j] = *(const float4*)&Vs[base];
      }
#pragma unroll
      for (int i = 0; i < 8; ++i) {
        float4 qa = *(const float4*)&Qs[((ty8 + i) << 6) + ((gk ^ tym) << 2)];
#pragma unroll
        for (int j = 0; j < 4; ++j) {
          sims[i][j] += qa.x * ka[j].x + qa.y * ka[j].y +
                        qa.z * ka[j].z + qa.w * ka[j].w;
          ipv[i][j]  += qa.x * va[j].x + qa.y * va[j].y +
                        qa.z * va[j].z + qa.w * va[j].w;
        }
      }
    }
    __syncthreads();  // Ks consumed; safe to overlay weight tile

    // elementwise: w = e * acosh(-c) / sqrt(c^2-1), stored bf16 over Ks
    unsigned int* Wt = (unsigned int*)Ks;  // row r: 32 uints (64 bf16)
#pragma unroll
    for (int i = 0; i < 8; ++i) {
      float wj[4];
#pragma unroll
      for (int j = 0; j < 4; ++j) {
        float c = ipv[i][j];
        float x = -c;
        float s2 = fmaxf(fmaf(x, x, -1.0f), EPSF);
        float rs = __builtin_amdgcn_rsqf(s2);
        float dist = __logf(fmaf(s2, rs, x));   // log(x + sqrt(x^2-1))
        float e = __expf(fmaf(-BETA, sims[i][j], -SHIFT));
        float w = e * dist * rs;
        wj[j] = w;
        Lp[i]  += e;
        WCp[i] += w * c;
        T0p[i] += w * v0r[j];
      }
      int base = ((ty8 + i) << 5) + ((tx ^ tym) << 1);
      Wt[base]     = pack_bf16(wj[0], wj[1]);
      Wt[base + 1] = pack_bf16(wj[2], wj[3]);
    }
    __syncthreads();

    // Phase B: T[s][d] += W[s][m] * Vr[m][d]  (W read back as bf16)
    const unsigned int* Wr = (const unsigned int*)Ks;
#pragma unroll 4
    for (int mm = 0; mm < 64; mm += 4) {
      const int mg = mm >> 2;
      float vb[4][4];
#pragma unroll
      for (int qd = 0; qd < 4; ++qd) {
        int rr = mm + qd;
        float4 t = *(const float4*)&Vs[(rr << 6) + ((tx ^ (rr >> 2)) << 2)];
        vb[qd][0] = t.x; vb[qd][1] = t.y; vb[qd][2] = t.z; vb[qd][3] = t.w;
      }
#pragma unroll
      for (int i = 0; i < 8; ++i) {
        int base = ((ty8 + i) << 5) + ((mg ^ tym) << 1);
        unsigned int p0 = Wr[base], p1 = Wr[base + 1];
        float w0 = bf16lo(p0), w1 = bf16hi(p0);
        float w2 = bf16lo(p1), w3 = bf16hi(p1);
#pragma unroll
        for (int j = 0; j < 4; ++j)
          accT[i][j] += w0 * vb[0][j] + w1 * vb[1][j] +
                        w2 * vb[2][j] + w3 * vb[3][j];
      }
    }
    __syncthreads();
  }

  // reduce row-scalars over the 16 tx lanes
#pragma unroll
  for (int i = 0; i < 8; ++i) {
#pragma unroll
    for (int off = 1; off < 16; off <<= 1) {
      Lp[i]  += __shfl_xor(Lp[i], off);
      WCp[i] += __shfl_xor(WCp[i], off);
      T0p[i] += __shfl_xor(T0p[i], off);
    }
  }

  const int rowP = (sl << 12) + rowQ;
#pragma unroll
  for (int i = 0; i < 8; ++i) {
    float4 v = make_float4(accT[i][0], accT[i][1], accT[i][2], accT[i][3]);
    *(float4*)&Tpart[(rowP + ty8 + i) * 64 + tx4] = v;
    if (tx == 0) {
      T0part[rowP + ty8 + i] = T0p[i];
      Lpart[rowP + ty8 + i]  = Lp[i];
      WCpart[rowP + ty8 + i] = WCp[i];
    }
  }
}

// ---------------------------------------------------------------------------
// Combine: one wave per (b,s) row, f64 internally.
// <tm,tm> = <t,t> + wc^2  (tangency identity; avoids 1e4x cancellation).
// ---------------------------------------------------------------------------
__global__ __launch_bounds__(256) void combine_kernel(
    const float* __restrict__ Q0, const float* __restrict__ Qr,
    const float* __restrict__ Tpart, const float* __restrict__ T0part,
    const float* __restrict__ Lpart, const float* __restrict__ WCpart,
    float* __restrict__ out, int nSl)
{
  int wid = (blockIdx.x << 2) + (threadIdx.x >> 6);
  int lane = threadIdx.x & 63;

  double Tsum = 0.0, T0 = 0.0, L = 0.0, WC = 0.0;
  for (int sli = 0; sli < nSl; ++sli) {
    int rp = (sli << 12) + wid;
    Tsum += (double)Tpart[rp * 64 + lane];
    T0 += (double)T0part[rp];
    L  += (double)Lpart[rp];
    WC += (double)WCpart[rp];
  }
  double qd = (double)Qr[wid * 64 + lane];
  double q0 = (double)Q0[wid];
  double invL = 1.0 / L;
  double td = Tsum * invL;
  double t0 = T0 * invL;
  double wc = WC * invL;

  double tt = td * td;
#pragma unroll
  for (int off = 1; off < 64; off <<= 1) tt += __shfl_xor(tt, off);
  tt -= t0 * t0;

  double mk = tt + wc * wc;
  double un = sqrt(fmax(mk, EPSD));
  double ch = cosh(un), shu = sinh(un) / un;

  double tmd = td + wc * qd;
  double tm0 = t0 + wc * q0;
  double zd = ch * qd + shu * tmd;
  double z0 = ch * q0 + shu * tm0;

  double p2 = zd * zd;
#pragma unroll
  for (int off = 1; off < 64; off <<= 1) p2 += __shfl_xor(p2, off);
  double yn = fmax(sqrt(p2), EPSD);
  double dl = acosh(fmax(z0, 1.0 + EPSD));
  out[wid * 64 + lane] = (float)(dl * zd / yn);
}

// ---------------------------------------------------------------------------
extern "C" void kernel_launch(void* const* d_in, const int* in_sizes, int n_in,
                              void* d_out, int out_size, void* d_ws, size_t ws_size,
                              hipStream_t stream)
{
  const float* queries = (const float*)d_in[0];
  const float* keys    = (const float*)d_in[1];
  const float* values  = (const float*)d_in[2];
  const float* Wq      = (const float*)d_in[3];
  const float* bq      = (const float*)d_in[4];
  const float* Wk      = (const float*)d_in[5];
  const float* bk      = (const float*)d_in[6];
  const float* Wv      = (const float*)d_in[7];
  const float* bv      = (const float*)d_in[8];
  float* out = (float*)d_out;
  float* ws  = (float*)d_ws;

  const size_t base = 1331200;  // floats before Tpart
  int SL = 16;
  {
    size_t need16 = (base + (size_t)16 * 4096 * 64 + 3 * (size_t)16 * 4096) * 4;
    size_t need8  = (base + (size_t)8  * 4096 * 64 + 3 * (size_t)8  * 4096) * 4;
    if (ws_size < need16) SL = (ws_size >= need8) ? 8 : 4;
  }
  const int nChunk = 4096 / SL / 64;  // 4 / 8 / 16

  float* Q0 = ws;                          // 4096
  float* Qr = ws + 4096;                   // 262144
  float* K0 = ws + 266240;                 // 8192
  float* Kr = ws + 274432;                 // 524288
  float* V0 = ws + 798720;                 // 8192
  float* Vr = ws + 806912;                 // 524288
  float* Tpart  = ws + base;               // SL*4096*64
  float* T0part = Tpart + (size_t)SL * 4096 * 64;
  float* Lpart  = T0part + SL * 4096;
  float* WCpart = Lpart + SL * 4096;

  proj_kernel<<<320, 256, 0, stream>>>(queries, keys, values, Wq, bq, Wk, bk,
                                       Wv, bv, Q0, Qr, K0, Kr, V0, Vr);
  attn_kernel<<<dim3(16, SL, 2), 256, 0, stream>>>(
      Q0, Qr, K0, Kr, V0, Vr, Tpart, T0part, Lpart, WCpart, nChunk);
  combine_kernel<<<1024, 256, 0, stream>>>(
      Q0, Qr, Tpart, T0part, Lpart, WCpart, out, SL);
}

// Round 5
// 172.558 us; speedup vs baseline: 1.4387x; 1.4387x over previous
//
#include <hip/hip_runtime.h>
#include <math.h>

#define BETA  0.125f    // 1/sqrt(64)
#define SHIFT 30.0f     // fixed softmax shift; logits bounded in [0.125, 68.5]
#define EPSF  1e-7f
#define EPSD  1e-7

typedef __attribute__((ext_vector_type(8))) short short8;
typedef __attribute__((ext_vector_type(4))) short short4v;
typedef __attribute__((ext_vector_type(4))) float f32x4;

__device__ __forceinline__ unsigned short bf16_rne(float x) {
  unsigned int u = __float_as_uint(x);
  return (unsigned short)((u + 0x7fffu + ((u >> 16) & 1u)) >> 16);
}
__device__ __forceinline__ float bf16_tof(unsigned short h) {
  return __uint_as_float(((unsigned int)h) << 16);
}
__device__ __forceinline__ void split2(float x, unsigned short& h, unsigned short& l) {
  unsigned int u = __float_as_uint(x);
  unsigned int hr = (u + 0x7fffu + ((u >> 16) & 1u)) & 0xffff0000u;  // RNE hi
  h = (unsigned short)(hr >> 16);
  l = bf16_rne(x - __uint_as_float(hr));
}

// ---------------------------------------------------------------------------
// Merged projection. Blocks 0..63: Q; 64..191: K; 192..319: V (double proj).
// Outputs per row: y0 = cosh (f32), spatial part split into bf16 hi/lo
// (row-major); V additionally transposed (Vth/Vtl [64][8192]).
// ---------------------------------------------------------------------------
__global__ __launch_bounds__(256) void proj_kernel(
    const float* __restrict__ Xq, const float* __restrict__ Xk,
    const float* __restrict__ Xv,
    const float* __restrict__ Wq, const float* __restrict__ bq,
    const float* __restrict__ Wk, const float* __restrict__ bk,
    const float* __restrict__ Wv, const float* __restrict__ bv,
    float* __restrict__ Q0, float* __restrict__ K0, float* __restrict__ V0,
    unsigned short* __restrict__ Qh, unsigned short* __restrict__ Ql,
    unsigned short* __restrict__ Kh, unsigned short* __restrict__ Kl,
    unsigned short* __restrict__ Vh, unsigned short* __restrict__ Vl,
    unsigned short* __restrict__ Vth, unsigned short* __restrict__ Vtl)
{
  __shared__ float Xs[64 * 64];
  __shared__ float Ws[64 * 64];

  const int bid = blockIdx.x;
  const float *X, *W, *bias;
  float* y0;
  unsigned short *yh, *yl;
  bool dbl, isV = false;
  int rowBase;
  if (bid < 64)       { X = Xq; W = Wq; bias = bq; y0 = Q0; yh = Qh; yl = Ql; rowBase = bid << 6;         dbl = false; }
  else if (bid < 192) { X = Xk; W = Wk; bias = bk; y0 = K0; yh = Kh; yl = Kl; rowBase = (bid - 64) << 6;  dbl = false; }
  else                { X = Xv; W = Wk; bias = bk; y0 = V0; yh = Vh; yl = Vl; rowBase = (bid - 192) << 6; dbl = true; isV = true; }

  const int tid = threadIdx.x;
  const int ty = tid >> 4, tx = tid & 15;
  const int ty4 = ty << 2, tx4 = tx << 2;

  float acc[4][4];
#pragma unroll
  for (int j = 0; j < 4; ++j) {
    float bj = bias[tx4 + j];
#pragma unroll
    for (int i = 0; i < 4; ++i) acc[i][j] = bj;
  }

  for (int kc = 0; kc < 4; ++kc) {
#pragma unroll
    for (int q = 0; q < 4; ++q) {
      int f = tid + (q << 8);
      int r = f >> 4, g = f & 15;
      int sw = (r << 6) + ((g ^ (r >> 2)) << 2);
      *(float4*)&Xs[sw] = *(const float4*)&X[(rowBase + r) * 256 + (kc << 6) + (g << 2)];
      *(float4*)&Ws[sw] = *(const float4*)&W[r * 256 + (kc << 6) + (g << 2)];
    }
    __syncthreads();
#pragma unroll 4
    for (int kk = 0; kk < 64; kk += 4) {
      const int gk = kk >> 2;
      float4 xa[4], wb[4];
#pragma unroll
      for (int i = 0; i < 4; ++i)
        xa[i] = *(const float4*)&Xs[((ty4 + i) << 6) + ((gk ^ ty) << 2)];
#pragma unroll
      for (int j = 0; j < 4; ++j)
        wb[j] = *(const float4*)&Ws[((tx4 + j) << 6) + ((gk ^ tx) << 2)];
#pragma unroll
      for (int i = 0; i < 4; ++i)
#pragma unroll
        for (int j = 0; j < 4; ++j)
          acc[i][j] += xa[i].x * wb[j].x + xa[i].y * wb[j].y +
                       xa[i].z * wb[j].z + xa[i].w * wb[j].w;
    }
    __syncthreads();
  }

  if (dbl) {
#pragma unroll
    for (int i = 0; i < 4; ++i) {
      float4 v = make_float4(acc[i][0], acc[i][1], acc[i][2], acc[i][3]);
      *(float4*)&Xs[((ty4 + i) << 6) + ((tx ^ ty) << 2)] = v;
    }
#pragma unroll
    for (int q = 0; q < 4; ++q) {
      int f = tid + (q << 8);
      int r = f >> 4, g = f & 15;
      int sw = (r << 6) + ((g ^ (r >> 2)) << 2);
      *(float4*)&Ws[sw] = *(const float4*)&Wv[(r << 6) + (g << 2)];
    }
#pragma unroll
    for (int j = 0; j < 4; ++j) {
      float bj = bv[tx4 + j];
#pragma unroll
      for (int i = 0; i < 4; ++i) acc[i][j] = bj;
    }
    __syncthreads();
#pragma unroll 4
    for (int kk = 0; kk < 64; kk += 4) {
      const int gk = kk >> 2;
      float4 xa[4], wb[4];
#pragma unroll
      for (int i = 0; i < 4; ++i)
        xa[i] = *(const float4*)&Xs[((ty4 + i) << 6) + ((gk ^ ty) << 2)];
#pragma unroll
      for (int j = 0; j < 4; ++j)
        wb[j] = *(const float4*)&Ws[((tx4 + j) << 6) + ((gk ^ tx) << 2)];
#pragma unroll
      for (int i = 0; i < 4; ++i)
#pragma unroll
        for (int j = 0; j < 4; ++j)
          acc[i][j] += xa[i].x * wb[j].x + xa[i].y * wb[j].y +
                       xa[i].z * wb[j].z + xa[i].w * wb[j].w;
    }
  }

  // expmap0 epilogue in registers + shuffles
  float n2p[4];
#pragma unroll
  for (int i = 0; i < 4; ++i)
    n2p[i] = acc[i][0] * acc[i][0] + acc[i][1] * acc[i][1] +
             acc[i][2] * acc[i][2] + acc[i][3] * acc[i][3];
#pragma unroll
  for (int i = 0; i < 4; ++i) {
    n2p[i] += __shfl_xor(n2p[i], 1);
    n2p[i] += __shfl_xor(n2p[i], 2);
    n2p[i] += __shfl_xor(n2p[i], 4);
    n2p[i] += __shfl_xor(n2p[i], 8);
  }
#pragma unroll
  for (int i = 0; i < 4; ++i) {
    float n = sqrtf(n2p[i]);
    float factor = fminf(3.5f / (n + EPSF), 1.0f);
    float xn = fmaxf(n * factor, EPSF);
    float et = __expf(xn);
    float rt = __builtin_amdgcn_rcpf(et);
    float ch = 0.5f * (et + rt);
    float sh = 0.5f * (et - rt);
    float scale = sh * factor * __builtin_amdgcn_rcpf(xn);
    int row = rowBase + ty4 + i;
    if (tx == 0) y0[row] = ch;
    unsigned short h[4], l[4];
#pragma unroll
    for (int j = 0; j < 4; ++j) split2(acc[i][j] * scale, h[j], l[j]);
    unsigned int* ph = (unsigned int*)(yh + row * 64 + tx4);
    ph[0] = (unsigned int)h[0] | ((unsigned int)h[1] << 16);
    ph[1] = (unsigned int)h[2] | ((unsigned int)h[3] << 16);
    unsigned int* pl = (unsigned int*)(yl + row * 64 + tx4);
    pl[0] = (unsigned int)l[0] | ((unsigned int)l[1] << 16);
    pl[1] = (unsigned int)l[2] | ((unsigned int)l[3] << 16);
    if (isV) {
#pragma unroll
      for (int j = 0; j < 4; ++j) {
        Vth[(tx4 + j) * 8192 + row] = h[j];
        Vtl[(tx4 + j) * 8192 + row] = l[j];
      }
    }
  }
}

// ---------------------------------------------------------------------------
// MFMA attention core. One wave = 32 s-rows x one m-slice; 4 waves/WG, zero
// __syncthreads (per-wave-private LDS for the W relayout). bf16-split dots:
// X.Y ~= XhYh + XhYl + XlYh (error ~1e-3 abs on c~300). 16x16x32 MFMA;
// A/B frag: [lane&15][(lane>>4)*8+j]; C/D: col=lane&15, row=(lane>>4)*4+reg.
// ---------------------------------------------------------------------------
__global__ void __attribute__((amdgpu_waves_per_eu(2, 2)))
__launch_bounds__(256) attn_kernel(
    const float* __restrict__ Q0g, const unsigned short* __restrict__ Qh,
    const unsigned short* __restrict__ Ql,
    const float* __restrict__ K0g, const unsigned short* __restrict__ Kh,
    const unsigned short* __restrict__ Kl,
    const float* __restrict__ V0g, const unsigned short* __restrict__ Vh,
    const unsigned short* __restrict__ Vl,
    const unsigned short* __restrict__ Vth, const unsigned short* __restrict__ Vtl,
    float* __restrict__ Tpart, float* __restrict__ T0part,
    float* __restrict__ Lpart, float* __restrict__ WCpart,
    int SL, int nChunk)
{
  __shared__ unsigned short Wlds[4 * 32 * 68];  // stride 68: conflict-free

  const int tid = threadIdx.x;
  const int wave = tid >> 6, lane = tid & 63;
  const int lm = lane & 15;   // tile col / A-row
  const int lg = lane >> 4;   // quad
  const int Wid = blockIdx.x * 4 + wave;
  const int slice = Wid % SL;
  const int sT = (Wid / SL) & 63;
  const int b = Wid / (SL * 64);
  const int sBase = b * 2048 + sT * 32;

  unsigned short* wbase = Wlds + wave * (32 * 68);

  // loop-invariant Q fragments [si][kstep][hi/lo]
  short8 qf[2][2][2];
#pragma unroll
  for (int si = 0; si < 2; ++si)
#pragma unroll
    for (int ks = 0; ks < 2; ++ks) {
      int idx = (sBase + si * 16 + lm) * 64 + ks * 32 + lg * 8;
      qf[si][ks][0] = *(const short8*)(Qh + idx);
      qf[si][ks][1] = *(const short8*)(Ql + idx);
    }
  float q0r[2][4];
#pragma unroll
  for (int si = 0; si < 2; ++si)
#pragma unroll
    for (int r = 0; r < 4; ++r)
      q0r[si][r] = Q0g[sBase + si * 16 + lg * 4 + r];

  f32x4 accT[2][4];
  float Lp[2][4], WCp[2][4], T0p[2][4];
#pragma unroll
  for (int si = 0; si < 2; ++si)
#pragma unroll
    for (int r = 0; r < 4; ++r) {
      Lp[si][r] = 0.f; WCp[si][r] = 0.f; T0p[si][r] = 0.f;
    }
#pragma unroll
  for (int si = 0; si < 2; ++si)
#pragma unroll
    for (int dj = 0; dj < 4; ++dj) accT[si][dj] = f32x4{0.f, 0.f, 0.f, 0.f};

  const int mSliceBase = b * 4096 + slice * (nChunk * 64);
  for (int mc = 0; mc < nChunk; ++mc) {
    const int mCh = mSliceBase + (mc << 6);
    float k0r[4], v0r[4];
#pragma unroll
    for (int mj = 0; mj < 4; ++mj) {
      k0r[mj] = K0g[mCh + mj * 16 + lm];
      v0r[mj] = V0g[mCh + mj * 16 + lm];
    }

    // Phase A: sims = Qr.Kr, ipv = Qr.Vr via split-bf16 MFMA
    f32x4 sims[2][4], ipv[2][4];
#pragma unroll
    for (int si = 0; si < 2; ++si)
#pragma unroll
      for (int mj = 0; mj < 4; ++mj) {
        sims[si][mj] = f32x4{0.f, 0.f, 0.f, 0.f};
        ipv[si][mj]  = f32x4{0.f, 0.f, 0.f, 0.f};
      }
#pragma unroll
    for (int mj = 0; mj < 4; ++mj) {
#pragma unroll
      for (int ks = 0; ks < 2; ++ks) {
        int bidx = (mCh + mj * 16 + lm) * 64 + ks * 32 + lg * 8;
        short8 kh = *(const short8*)(Kh + bidx);
        short8 kl = *(const short8*)(Kl + bidx);
        short8 vh = *(const short8*)(Vh + bidx);
        short8 vl = *(const short8*)(Vl + bidx);
#pragma unroll
        for (int si = 0; si < 2; ++si) {
          sims[si][mj] = __builtin_amdgcn_mfma_f32_16x16x32_bf16(qf[si][ks][0], kh, sims[si][mj], 0, 0, 0);
          sims[si][mj] = __builtin_amdgcn_mfma_f32_16x16x32_bf16(qf[si][ks][0], kl, sims[si][mj], 0, 0, 0);
          sims[si][mj] = __builtin_amdgcn_mfma_f32_16x16x32_bf16(qf[si][ks][1], kh, sims[si][mj], 0, 0, 0);
          ipv[si][mj]  = __builtin_amdgcn_mfma_f32_16x16x32_bf16(qf[si][ks][0], vh, ipv[si][mj], 0, 0, 0);
          ipv[si][mj]  = __builtin_amdgcn_mfma_f32_16x16x32_bf16(qf[si][ks][0], vl, ipv[si][mj], 0, 0, 0);
          ipv[si][mj]  = __builtin_amdgcn_mfma_f32_16x16x32_bf16(qf[si][ks][1], vh, ipv[si][mj], 0, 0, 0);
        }
      }
    }

    // elementwise: rank-1 time-component correction + w = e*acosh(-c)*rsq(c^2-1)
#pragma unroll
    for (int si = 0; si < 2; ++si)
#pragma unroll
      for (int mj = 0; mj < 4; ++mj)
#pragma unroll
        for (int r = 0; r < 4; ++r) {
          float c  = ipv[si][mj][r]  - q0r[si][r] * v0r[mj];
          float sm = sims[si][mj][r] - q0r[si][r] * k0r[mj];
          float x = -c;
          float s2 = fmaxf(fmaf(x, x, -1.0f), EPSF);
          float rs = __builtin_amdgcn_rsqf(s2);
          float dist = __logf(fmaf(s2, rs, x));  // log(x + sqrt(x^2-1))
          float e = __expf(fmaf(-BETA, sm, -SHIFT));
          float w = e * dist * rs;
          unsigned short wu = bf16_rne(w);
          float wb = bf16_tof(wu);               // keep WC/T0 consistent with T
          Lp[si][r]  += e;
          WCp[si][r] += wb * c;
          T0p[si][r] += wb * v0r[mj];
          wbase[(si * 16 + lg * 4 + r) * 68 + mj * 16 + lm] = wu;
        }

    // Phase B: T[s][d] += W[s][m] * V[m][d]  (A = W from LDS, B = Vt hi/lo)
#pragma unroll
    for (int ks = 0; ks < 2; ++ks) {
      short8 wa[2];
#pragma unroll
      for (int si = 0; si < 2; ++si) {
        const unsigned short* p = wbase + (si * 16 + lm) * 68 + ks * 32 + lg * 8;
        short4v a0 = *(const short4v*)p;
        short4v a1 = *(const short4v*)(p + 4);
        wa[si] = __builtin_shufflevector(a0, a1, 0, 1, 2, 3, 4, 5, 6, 7);
      }
#pragma unroll
      for (int dj = 0; dj < 4; ++dj) {
        int vidx = (dj * 16 + lm) * 8192 + mCh + ks * 32 + lg * 8;
        short8 th = *(const short8*)(Vth + vidx);
        short8 tl = *(const short8*)(Vtl + vidx);
#pragma unroll
        for (int si = 0; si < 2; ++si) {
          accT[si][dj] = __builtin_amdgcn_mfma_f32_16x16x32_bf16(wa[si], th, accT[si][dj], 0, 0, 0);
          accT[si][dj] = __builtin_amdgcn_mfma_f32_16x16x32_bf16(wa[si], tl, accT[si][dj], 0, 0, 0);
        }
      }
    }
  }

  // reduce row scalars across the 16 col-lanes of each quad group
#pragma unroll
  for (int si = 0; si < 2; ++si)
#pragma unroll
    for (int r = 0; r < 4; ++r)
#pragma unroll
      for (int off = 1; off < 16; off <<= 1) {
        Lp[si][r]  += __shfl_xor(Lp[si][r], off);
        WCp[si][r] += __shfl_xor(WCp[si][r], off);
        T0p[si][r] += __shfl_xor(T0p[si][r], off);
      }

  const int rowP = (slice << 12) + sBase;
#pragma unroll
  for (int si = 0; si < 2; ++si)
#pragma unroll
    for (int r = 0; r < 4; ++r) {
      int row = rowP + si * 16 + lg * 4 + r;
#pragma unroll
      for (int dj = 0; dj < 4; ++dj)
        Tpart[row * 64 + dj * 16 + lm] = accT[si][dj][r];
      if (lm == 0) {
        Lpart[row]  = Lp[si][r];
        WCpart[row] = WCp[si][r];
        T0part[row] = T0p[si][r];
      }
    }
}

// ---------------------------------------------------------------------------
// Combine: one wave per (b,s) row, f64 internally.
// <tm,tm> = <t,t> + wc^2  (tangency identity; avoids 1e4x cancellation).
// ---------------------------------------------------------------------------
__global__ __launch_bounds__(256) void combine_kernel(
    const float* __restrict__ Q0, const unsigned short* __restrict__ Qh,
    const unsigned short* __restrict__ Ql,
    const float* __restrict__ Tpart, const float* __restrict__ T0part,
    const float* __restrict__ Lpart, const float* __restrict__ WCpart,
    float* __restrict__ out, int nSl)
{
  int wid = (blockIdx.x << 2) + (threadIdx.x >> 6);
  int lane = threadIdx.x & 63;

  double Tsum = 0.0, T0 = 0.0, L = 0.0, WC = 0.0;
  for (int sli = 0; sli < nSl; ++sli) {
    int rp = (sli << 12) + wid;
    Tsum += (double)Tpart[rp * 64 + lane];
    T0 += (double)T0part[rp];
    L  += (double)Lpart[rp];
    WC += (double)WCpart[rp];
  }
  int qi = wid * 64 + lane;
  double qd = (double)(bf16_tof(Qh[qi]) + bf16_tof(Ql[qi]));
  double q0 = (double)Q0[wid];
  double invL = 1.0 / L;
  double td = Tsum * invL;
  double t0 = T0 * invL;
  double wc = WC * invL;

  double tt = td * td;
#pragma unroll
  for (int off = 1; off < 64; off <<= 1) tt += __shfl_xor(tt, off);
  tt -= t0 * t0;

  double mk = tt + wc * wc;
  double un = sqrt(fmax(mk, EPSD));
  double ch = cosh(un), shu = sinh(un) / un;

  double tmd = td + wc * qd;
  double tm0 = t0 + wc * q0;
  double zd = ch * qd + shu * tmd;
  double z0 = ch * q0 + shu * tm0;

  double p2 = zd * zd;
#pragma unroll
  for (int off = 1; off < 64; off <<= 1) p2 += __shfl_xor(p2, off);
  double yn = fmax(sqrt(p2), EPSD);
  double dl = acosh(fmax(z0, 1.0 + EPSD));
  out[wid * 64 + lane] = (float)(dl * zd / yn);
}

// ---------------------------------------------------------------------------
extern "C" void kernel_launch(void* const* d_in, const int* in_sizes, int n_in,
                              void* d_out, int out_size, void* d_ws, size_t ws_size,
                              hipStream_t stream)
{
  const float* queries = (const float*)d_in[0];
  const float* keys    = (const float*)d_in[1];
  const float* values  = (const float*)d_in[2];
  const float* Wq      = (const float*)d_in[3];
  const float* bq      = (const float*)d_in[4];
  const float* Wk      = (const float*)d_in[5];
  const float* bk      = (const float*)d_in[6];
  const float* Wv      = (const float*)d_in[7];
  const float* bv      = (const float*)d_in[8];
  float* out = (float*)d_out;
  float* ws  = (float*)d_ws;

  // f32-unit workspace layout
  const size_t base = 1855488;
  auto need = [&](size_t sl) {
    return (base + sl * 4096 * 64 + 3 * sl * 4096) * 4;
  };
  int SL = 16;
  if (ws_size < need(16)) SL = (ws_size >= need(8)) ? 8 : 4;
  const int nChunk = 4096 / (SL * 64);

  float* Q0 = ws;                                   // 4096
  float* K0 = ws + 4096;                            // 8192
  float* V0 = ws + 12288;                           // 8192
  unsigned short* Qh  = (unsigned short*)(ws + 20480);    // 4096*64 u16
  unsigned short* Ql  = (unsigned short*)(ws + 151552);
  unsigned short* Kh  = (unsigned short*)(ws + 282624);   // 8192*64 u16
  unsigned short* Kl  = (unsigned short*)(ws + 544768);
  unsigned short* Vh  = (unsigned short*)(ws + 806912);
  unsigned short* Vl  = (unsigned short*)(ws + 1069056);
  unsigned short* Vth = (unsigned short*)(ws + 1331200);  // [64][8192] u16
  unsigned short* Vtl = (unsigned short*)(ws + 1593344);
  float* Tpart  = ws + base;                        // SL*4096*64
  float* T0part = Tpart + (size_t)SL * 4096 * 64;
  float* Lpart  = T0part + (size_t)SL * 4096;
  float* WCpart = Lpart + (size_t)SL * 4096;

  proj_kernel<<<320, 256, 0, stream>>>(queries, keys, values, Wq, bq, Wk, bk,
                                       Wv, bv, Q0, K0, V0, Qh, Ql, Kh, Kl,
                                       Vh, Vl, Vth, Vtl);
  attn_kernel<<<32 * SL, 256, 0, stream>>>(
      Q0, Qh, Ql, K0, Kh, Kl, V0, Vh, Vl, Vth, Vtl,
      Tpart, T0part, Lpart, WCpart, SL, nChunk);
  combine_kernel<<<1024, 256, 0, stream>>>(
      Q0, Qh, Ql, Tpart, T0part, Lpart, WCpart, out, SL);
}